// Round 11
// baseline (558.504 us; speedup 1.0000x reference)
//
#include <hip/hip_runtime.h>
#include <math.h>

#define N_NODES 40000
#define E_EDGES 640000
#define IN_DIM 128
#define EDGE_DIM 64
#define HID 128
#define EB 10000   // edge blocks for k_edge (E/64)
#define NPART (EB * 4)

typedef unsigned int u32;
typedef unsigned short u16;
typedef __attribute__((ext_vector_type(4))) float f32x4;
typedef __attribute__((ext_vector_type(8))) short bf16x8;

__device__ __forceinline__ float bf_lo(u32 d) { return __uint_as_float(d << 16); }
__device__ __forceinline__ float bf_hi(u32 d) { return __uint_as_float(d & 0xffff0000u); }
__device__ __forceinline__ u16 f2bf(float f) {            // RNE
    u32 u = __float_as_uint(f);
    return (u16)((u + 0x7fffu + ((u >> 16) & 1u)) >> 16);
}
__device__ __forceinline__ u32 pack_bf(float lo, float hi) {
    return ((u32)f2bf(hi) << 16) | (u32)f2bf(lo);
}

// ---------------------------------------------------------------------------
// ws layout (8-B aligned block first):
//   sde  [E] uint2 : CSR payload (dst, bits(-exp(score)))
//   P1b [N*HID] u16, P2b [N*HID] u16, xb [N*IN] u16
//   Whtb [HID*EDGE_DIM] u16, WnAT [HID*IN] u16, WnBT [HID*IN] u16, fttb [IN*IN] u16
//   partials [NPART] f32, sumExp [1] f32
//   counts [N] u32, off [N+1] u32, cur [N] u32
// ---------------------------------------------------------------------------

// fused: xb cast + weight transpose/cast + degree histogram.
// counts[] zeroed by hipMemsetAsync before this kernel.
__global__ __launch_bounds__(256) void k_pre(const float* __restrict__ x,
                                             const float* __restrict__ Whw,
                                             const float* __restrict__ Wnw,
                                             const float* __restrict__ ftw,
                                             const int* __restrict__ eidx,
                                             u16* __restrict__ xb,
                                             u32* __restrict__ counts,
                                             u16* __restrict__ Whtb,
                                             u16* __restrict__ WnAT,
                                             u16* __restrict__ WnBT,
                                             u16* __restrict__ fttb) {
    if (blockIdx.x < 20000) {
        int i = blockIdx.x * 256 + threadIdx.x;   // covers N*IN_DIM exactly
        xb[i] = f2bf(x[i]);
    } else if (blockIdx.x < 20224) {
        int i = (blockIdx.x - 20000) * 256 + threadIdx.x;   // 224*256 = 57344
        if (i < 8192) {
            int h = i >> 6, k = i & 63;
            Whtb[i] = f2bf(Whw[k * HID + h]);
        } else if (i < 24576) {
            int j = i - 8192, h = j >> 7, k = j & 127;
            WnAT[j] = f2bf(Wnw[k * HID + h]);
        } else if (i < 40960) {
            int j = i - 24576, h = j >> 7, k = j & 127;
            WnBT[j] = f2bf(Wnw[(IN_DIM + k) * HID + h]);
        } else {
            int j = i - 40960, h = j >> 7, k = j & 127;
            fttb[j] = f2bf(ftw[k * IN_DIM + h]);
        }
    } else {   // histogram: E exactly (2500 blocks)
        int e = (blockIdx.x - 20224) * 256 + threadIdx.x;
        atomicAdd(&counts[eidx[e]], 1u);
    }
}

__global__ __launch_bounds__(1024) void k_scan(const u32* __restrict__ counts,
                                               u32* __restrict__ off,
                                               u32* __restrict__ cur) {
    __shared__ u32 sums[1024];
    const int t = threadIdx.x;
    const int CH = 40;
    u32 local[CH];
    u32 s = 0;
    const int base = t * CH;
#pragma unroll
    for (int i = 0; i < CH; ++i) {
        int idx = base + i;
        u32 c = (idx < N_NODES) ? counts[idx] : 0u;
        local[i] = s;
        s += c;
    }
    sums[t] = s;
    __syncthreads();
    for (int o = 1; o < 1024; o <<= 1) {
        u32 v = (t >= o) ? sums[t - o] : 0u;
        __syncthreads();
        sums[t] += v;
        __syncthreads();
    }
    const u32 pre = sums[t] - s;
#pragma unroll
    for (int i = 0; i < CH; ++i) {
        int idx = base + i;
        if (idx < N_NODES) {
            u32 v = pre + local[i];
            off[idx] = v;
            cur[idx] = v;
        }
    }
    if (t == 1023) off[N_NODES] = sums[1023];
}

// MFMA node projection: P1 = xb@WnA + (Whb+Wnb), P2 = xb@WnB  (bf16 out)
__global__ __launch_bounds__(256) void k_proj(const u16* __restrict__ xb,
                                              const u16* __restrict__ WnAT,
                                              const u16* __restrict__ WnBT,
                                              const float* __restrict__ Whb,
                                              const float* __restrict__ Wnb,
                                              u16* __restrict__ P1b,
                                              u16* __restrict__ P2b) {
    const int t = threadIdx.x, w = t >> 6, lane = t & 63;
    const int mrow = lane & 15, quad = lane >> 4;
    const int rowBase = blockIdx.x * 64 + w * 16;

    bf16x8 a[4];
    const u16* ar = xb + (size_t)(rowBase + mrow) * IN_DIM + quad * 8;
#pragma unroll
    for (int ks = 0; ks < 4; ++ks) a[ks] = *(const bf16x8*)(ar + ks * 32);

#pragma unroll
    for (int nt = 0; nt < 8; ++nt) {
        const u16* b1p = WnAT + (size_t)(nt * 16 + mrow) * IN_DIM + quad * 8;
        const u16* b2p = WnBT + (size_t)(nt * 16 + mrow) * IN_DIM + quad * 8;
        f32x4 c1 = {0.f, 0.f, 0.f, 0.f}, c2 = {0.f, 0.f, 0.f, 0.f};
#pragma unroll
        for (int ks = 0; ks < 4; ++ks) {
            c1 = __builtin_amdgcn_mfma_f32_16x16x32_bf16(a[ks], *(const bf16x8*)(b1p + ks * 32), c1, 0, 0, 0);
            c2 = __builtin_amdgcn_mfma_f32_16x16x32_bf16(a[ks], *(const bf16x8*)(b2p + ks * 32), c2, 0, 0, 0);
        }
        const int col = nt * 16 + mrow;
        const float bias = Whb[col] + Wnb[col];
#pragma unroll
        for (int r = 0; r < 4; ++r) {
            int row = rowBase + quad * 4 + r;
            P1b[(size_t)row * HID + col] = f2bf(c1[r] + bias);
            P2b[(size_t)row * HID + col] = f2bf(c2[r]);
        }
    }
}

// Wave-autonomous MFMA edge kernel + fused CSR fill. No __syncthreads.
// R9 config (best measured: 143.8 us): 16 edges/wave, NT ea loads keep the
// 20 MB P tables L2-resident, R0 mrow==0 4x4-serial CSR fill.
__global__ __launch_bounds__(256) void k_edge(const int* __restrict__ eidx,
                                              const float* __restrict__ ea,
                                              const u16* __restrict__ Whtb,
                                              const u16* __restrict__ P1b,
                                              const u16* __restrict__ P2b,
                                              const float* __restrict__ we,
                                              u32* __restrict__ cur,
                                              uint2* __restrict__ sde,
                                              float* __restrict__ partials) {
    __shared__ u32 Psp[4][16][68];   // per-wave slices; stride 68 breaks pow2 banks
    const int t = threadIdx.x, w = t >> 6, lane = t & 63;
    const int e0 = blockIdx.x * 64 + w * 16;
    const int mrow = lane & 15, quad = lane >> 4;

    // --- issue ALL global loads up-front (gather + A-row) ---
    const int m = lane >> 2, c4 = lane & 3;   // lane -> edge m, quarter c4
    const int srcm = eidx[e0 + m];
    const int dstm = eidx[E_EDGES + e0 + m];
    const uint4* p1 = (const uint4*)(P1b + (size_t)srcm * HID + c4 * 32);
    const uint4* p2 = (const uint4*)(P2b + (size_t)dstm * HID + c4 * 32);
    uint4 pa[4], pb[4];
#pragma unroll
    for (int i = 0; i < 4; ++i) { pa[i] = p1[i]; pb[i] = p2[i]; }

    const f32x4* arow = (const f32x4*)(ea + (size_t)(e0 + mrow) * EDGE_DIM + quad * 8);
    f32x4 f0 = __builtin_nontemporal_load(arow);       // +0
    f32x4 f1 = __builtin_nontemporal_load(arow + 1);   // +4
    f32x4 f2 = __builtin_nontemporal_load(arow + 8);   // +32
    f32x4 f3 = __builtin_nontemporal_load(arow + 9);   // +36

    // --- pack node term into this wave's LDS slice ---
#pragma unroll
    for (int i = 0; i < 4; ++i) {
        u32 da[4] = {pa[i].x, pa[i].y, pa[i].z, pa[i].w};
        u32 db[4] = {pb[i].x, pb[i].y, pb[i].z, pb[i].w};
        uint4 o;
        o.x = pack_bf(bf_lo(da[0]) + bf_lo(db[0]), bf_hi(da[0]) + bf_hi(db[0]));
        o.y = pack_bf(bf_lo(da[1]) + bf_lo(db[1]), bf_hi(da[1]) + bf_hi(db[1]));
        o.z = pack_bf(bf_lo(da[2]) + bf_lo(db[2]), bf_hi(da[2]) + bf_hi(db[2]));
        o.w = pack_bf(bf_lo(da[3]) + bf_lo(db[3]), bf_hi(da[3]) + bf_hi(db[3]));
        *(uint4*)&Psp[w][m][c4 * 16 + i * 4] = o;
    }

    // --- A fragments from f0..f3 ---
    bf16x8 a0, a1;
    a0[0] = (short)f2bf(f0[0]); a0[1] = (short)f2bf(f0[1]);
    a0[2] = (short)f2bf(f0[2]); a0[3] = (short)f2bf(f0[3]);
    a0[4] = (short)f2bf(f1[0]); a0[5] = (short)f2bf(f1[1]);
    a0[6] = (short)f2bf(f1[2]); a0[7] = (short)f2bf(f1[3]);
    a1[0] = (short)f2bf(f2[0]); a1[1] = (short)f2bf(f2[1]);
    a1[2] = (short)f2bf(f2[2]); a1[3] = (short)f2bf(f2[3]);
    a1[4] = (short)f2bf(f3[0]); a1[5] = (short)f2bf(f3[1]);
    a1[6] = (short)f2bf(f3[2]); a1[7] = (short)f2bf(f3[3]);

    // --- MFMA over 8 n-tiles; fuse +Psum, relu, *we (wave-local LDS, no barrier) ---
    float wsum[4] = {0.f, 0.f, 0.f, 0.f};
    const u16* bbase = Whtb + (size_t)mrow * EDGE_DIM + quad * 8;
#pragma unroll
    for (int nt = 0; nt < 8; ++nt) {
        const u16* bp = bbase + nt * 16 * EDGE_DIM;
        bf16x8 b0 = *(const bf16x8*)(bp);
        bf16x8 b1 = *(const bf16x8*)(bp + 32);
        f32x4 c = {0.f, 0.f, 0.f, 0.f};
        c = __builtin_amdgcn_mfma_f32_16x16x32_bf16(a0, b0, c, 0, 0, 0);
        c = __builtin_amdgcn_mfma_f32_16x16x32_bf16(a1, b1, c, 0, 0, 0);
        float wv = we[nt * 16 + mrow];
#pragma unroll
        for (int r = 0; r < 4; ++r) {
            u32 u = Psp[w][quad * 4 + r][nt * 8 + (mrow >> 1)];
            float p = (mrow & 1) ? bf_hi(u) : bf_lo(u);
            wsum[r] += fmaxf(c[r] + p, 0.f) * wv;
        }
    }

    // --- reduce across the 16 lanes of each quad group ---
#pragma unroll
    for (int off = 1; off < 16; off <<= 1) {
#pragma unroll
        for (int r = 0; r < 4; ++r) wsum[r] += __shfl_xor(wsum[r], off, 16);
    }
    float ex[4]; float s4 = 0.f;
#pragma unroll
    for (int r = 0; r < 4; ++r) { ex[r] = __expf(wsum[r]); s4 += ex[r]; }

    // --- fused CSR fill: R0 exact pattern (mrow==0 lanes, 4 serial each) ---
    if (mrow == 0) {
#pragma unroll
        for (int r = 0; r < 4; ++r) {
            int e = e0 + quad * 4 + r;
            int s = eidx[e];
            int d = eidx[E_EDGES + e];
            u32 pos = atomicAdd(&cur[s], 1u);
            sde[pos] = make_uint2((u32)d, __float_as_uint(-ex[r]));
        }
    }

    // --- per-wave partial (plain store, no atomics) ---
    s4 += __shfl_xor(s4, 16, 64);
    s4 += __shfl_xor(s4, 32, 64);
    if (lane == 0) partials[blockIdx.x * 4 + w] = s4;
}

// block 0: reduce partials -> sumExp. blocks 1..N/4: one WAVE per node,
// out[n][:] = sum_{edges of n} (-exp_e) * xb[dst][:]   (RAW — invS in k_final)
// Gather shape: four 16-lane groups each fetch a DIFFERENT edge row at
// 16 B/lane (uint4) — one instruction = 4 rows (1 KB) vs 1 row (256 B).
// Lanes past cnt carry zeroed sde (row 0, weight +0.0) => no masking needed.
__global__ __launch_bounds__(256) void k_accum(const u32* __restrict__ off,
                                               const uint2* __restrict__ sde,
                                               const float* __restrict__ partials,
                                               float* __restrict__ sumExp,
                                               const u16* __restrict__ xb,
                                               float* __restrict__ out) {
    if (blockIdx.x == 0) {   // fused k_sum (saves a launch)
        float s = 0.f;
        for (int i = threadIdx.x; i < NPART; i += 256) s += partials[i];
#pragma unroll
        for (int o = 1; o < 64; o <<= 1) s += __shfl_xor(s, o, 64);
        __shared__ float ws4[4];
        if ((threadIdx.x & 63) == 0) ws4[threadIdx.x >> 6] = s;
        __syncthreads();
        if (threadIdx.x == 0) sumExp[0] = ws4[0] + ws4[1] + ws4[2] + ws4[3];
        return;
    }
    const int lane = threadIdx.x & 63;
    const int g = lane >> 4, sub = lane & 15;   // group 0..3, 16 lanes each
    const int n = (blockIdx.x - 1) * 4 + (threadIdx.x >> 6);
    const u32 o0 = off[n], o1 = off[n + 1];

    float acc[8] = {0.f, 0.f, 0.f, 0.f, 0.f, 0.f, 0.f, 0.f};

    for (u32 base = o0; base < o1; base += 64) {
        u32 j = base + (u32)lane;
        uint2 dv = make_uint2(0u, 0u);     // zeroed => row 0, weight +0.0
        if (j < o1) {
            dv.x = __builtin_nontemporal_load(&sde[j].x);
            dv.y = __builtin_nontemporal_load(&sde[j].y);
        }
        const int cnt = (int)min(64u, o1 - base);
        for (int jj = 0; jj < cnt; jj += 16) {   // 4 quads of 4 rows in flight
            float av[4]; uint4 q[4];
#pragma unroll
            for (int b = 0; b < 4; ++b) {
                int sl = jj + b * 4 + g;          // <= 63 always
                u32 dr = __shfl(dv.x, sl, 64);
                av[b] = __uint_as_float(__shfl(dv.y, sl, 64));
                q[b] = ((const uint4*)(xb + (size_t)dr * IN_DIM))[sub];
            }
#pragma unroll
            for (int b = 0; b < 4; ++b) {
                acc[0] = fmaf(av[b], bf_lo(q[b].x), acc[0]);
                acc[1] = fmaf(av[b], bf_hi(q[b].x), acc[1]);
                acc[2] = fmaf(av[b], bf_lo(q[b].y), acc[2]);
                acc[3] = fmaf(av[b], bf_hi(q[b].y), acc[3]);
                acc[4] = fmaf(av[b], bf_lo(q[b].z), acc[4]);
                acc[5] = fmaf(av[b], bf_hi(q[b].z), acc[5]);
                acc[6] = fmaf(av[b], bf_lo(q[b].w), acc[6]);
                acc[7] = fmaf(av[b], bf_hi(q[b].w), acc[7]);
            }
        }
    }

    // fold the 4 group-partials (lanes l, l^16, l^32, l^48 share columns)
#pragma unroll
    for (int k = 0; k < 8; ++k) {
        acc[k] += __shfl_xor(acc[k], 16, 64);
        acc[k] += __shfl_xor(acc[k], 32, 64);
    }
    if (g == 0) {   // lanes 0..15 write the 128-float row (two float4 each)
        float* op = out + (size_t)n * IN_DIM + sub * 8;
        float4 v0 = make_float4(acc[0], acc[1], acc[2], acc[3]);
        float4 v1 = make_float4(acc[4], acc[5], acc[6], acc[7]);
        *(float4*)op = v0;
        *(float4*)(op + 4) = v1;
    }
}

// MFMA finisher: out = y + y@ft + ftb, y = x + invS*local_raw(out in-place).
__global__ __launch_bounds__(256) void k_final(const float* __restrict__ x,
                                               const u16* __restrict__ fttb,
                                               const float* __restrict__ ftb,
                                               const float* __restrict__ sumExp,
                                               float* __restrict__ out) {
    __shared__ u32 ybp[64][68];   // packed bf16 y
    const float invS = 1.0f / sumExp[0];
    const int t = threadIdx.x;
    const int rb = blockIdx.x * 64;

    {   // stage y = x + invS*local as packed bf16
        const int rr = t >> 2, seg = t & 3;
        const float4* xp = (const float4*)(x + (size_t)(rb + rr) * IN_DIM + seg * 32);
        const float4* lp = (const float4*)(out + (size_t)(rb + rr) * IN_DIM + seg * 32);
#pragma unroll
        for (int i = 0; i < 4; ++i) {
            float4 xa = xp[2 * i], xc = xp[2 * i + 1];
            float4 la = lp[2 * i], lc = lp[2 * i + 1];
            uint4 o;
            o.x = pack_bf(fmaf(invS, la.x, xa.x), fmaf(invS, la.y, xa.y));
            o.y = pack_bf(fmaf(invS, la.z, xa.z), fmaf(invS, la.w, xa.w));
            o.z = pack_bf(fmaf(invS, lc.x, xc.x), fmaf(invS, lc.y, xc.y));
            o.w = pack_bf(fmaf(invS, lc.z, xc.z), fmaf(invS, lc.w, xc.w));
            *(uint4*)&ybp[rr][seg * 16 + i * 4] = o;
        }
    }
    __syncthreads();

    const int w = t >> 6, lane = t & 63;
    const int mrow = lane & 15, quad = lane >> 4;
    const int rowBase = rb + w * 16;

    bf16x8 a[4];
#pragma unroll
    for (int ks = 0; ks < 4; ++ks)
        a[ks] = *(const bf16x8*)&ybp[w * 16 + mrow][ks * 16 + quad * 4];

#pragma unroll
    for (int nt = 0; nt < 8; ++nt) {
        const u16* bp = fttb + (size_t)(nt * 16 + mrow) * IN_DIM + quad * 8;
        f32x4 c = {0.f, 0.f, 0.f, 0.f};
#pragma unroll
        for (int ks = 0; ks < 4; ++ks)
            c = __builtin_amdgcn_mfma_f32_16x16x32_bf16(a[ks], *(const bf16x8*)(bp + ks * 32), c, 0, 0, 0);
        const int col = nt * 16 + mrow;
        const float fb = ftb[col];
#pragma unroll
        for (int r = 0; r < 4; ++r) {
            int row = rowBase + quad * 4 + r;
            size_t idx = (size_t)row * IN_DIM + col;
            float y = fmaf(invS, out[idx], x[idx]);   // exact fp32 y term
            out[idx] = y + c[r] + fb;
        }
    }
}

extern "C" void kernel_launch(void* const* d_in, const int* in_sizes, int n_in,
                              void* d_out, int out_size, void* d_ws, size_t ws_size,
                              hipStream_t stream) {
    const float* x    = (const float*)d_in[0];
    const int*   eidx = (const int*)d_in[1];
    const float* ea   = (const float*)d_in[2];
    const float* Whw  = (const float*)d_in[3];
    const float* Whb  = (const float*)d_in[4];
    const float* Wnw  = (const float*)d_in[5];
    const float* Wnb  = (const float*)d_in[6];
    const float* we   = (const float*)d_in[7];
    const float* ftw  = (const float*)d_in[8];
    const float* ftb  = (const float*)d_in[9];
    float* out = (float*)d_out;

    uint2* sde      = (uint2*)d_ws;                       // 8-B aligned first
    u16*   P1b      = (u16*)(sde + (size_t)E_EDGES);
    u16*   P2b      = P1b + (size_t)N_NODES * HID;
    u16*   xb       = P2b + (size_t)N_NODES * HID;
    u16*   Whtb     = xb + (size_t)N_NODES * IN_DIM;
    u16*   WnAT     = Whtb + (size_t)EDGE_DIM * HID;
    u16*   WnBT     = WnAT + (size_t)HID * IN_DIM;
    u16*   fttb     = WnBT + (size_t)HID * IN_DIM;
    float* partials = (float*)(fttb + (size_t)IN_DIM * IN_DIM);
    float* sumExp   = partials + NPART;
    u32*   counts   = (u32*)(sumExp + 1);
    u32*   off      = counts + N_NODES;
    u32*   cur      = off + N_NODES + 1;

    hipMemsetAsync(counts, 0, (size_t)N_NODES * sizeof(u32), stream);
    k_pre  <<<22724, 256, 0, stream>>>(x, Whw, Wnw, ftw, eidx, xb, counts,
                                       Whtb, WnAT, WnBT, fttb);
    k_scan <<<1, 1024, 0, stream>>>(counts, off, cur);
    k_proj <<<N_NODES / 64, 256, 0, stream>>>(xb, WnAT, WnBT, Whb, Wnb, P1b, P2b);
    k_edge <<<EB, 256, 0, stream>>>(eidx, ea, Whtb, P1b, P2b, we, cur, sde, partials);
    k_accum<<<N_NODES / 4 + 1, 256, 0, stream>>>(off, sde, partials, sumExp, xb, out);
    k_final<<<N_NODES / 64, 256, 0, stream>>>(x, fttb, ftb, sumExp, out);
}

// Round 13
// 504.202 us; speedup vs baseline: 1.1077x; 1.1077x over previous
//
#include <hip/hip_runtime.h>
#include <math.h>

#define N_NODES 40000
#define E_EDGES 640000
#define IN_DIM 128
#define EDGE_DIM 64
#define HID 128
#define EBP 2500          // persistent k_edge blocks; 4 waves x 4 batches each
#define NWAVE 10000       // EBP * 4 waves
#define ESTEP 160000      // NWAVE * 16 edges per pipeline step
#define NPART NWAVE

typedef unsigned int u32;
typedef unsigned short u16;
typedef __attribute__((ext_vector_type(4))) float f32x4;
typedef __attribute__((ext_vector_type(8))) short bf16x8;

__device__ __forceinline__ float bf_lo(u32 d) { return __uint_as_float(d << 16); }
__device__ __forceinline__ float bf_hi(u32 d) { return __uint_as_float(d & 0xffff0000u); }
__device__ __forceinline__ u16 f2bf(float f) {            // RNE
    u32 u = __float_as_uint(f);
    return (u16)((u + 0x7fffu + ((u >> 16) & 1u)) >> 16);
}
__device__ __forceinline__ u32 pack_bf(float lo, float hi) {
    return ((u32)f2bf(hi) << 16) | (u32)f2bf(lo);
}

// ---------------------------------------------------------------------------
// ws layout (8-B aligned block first):
//   sde  [E] uint2 : CSR payload (dst, bits(-exp(score)))
//   P1b [N*HID] u16, P2b [N*HID] u16, xb [N*IN] u16
//   Whtb [HID*EDGE_DIM] u16, WnAT [HID*IN] u16, WnBT [HID*IN] u16, fttb [IN*IN] u16
//   partials [NPART] f32, sumExp [1] f32
//   counts [N] u32, off [N+1] u32, cur [N] u32
// ---------------------------------------------------------------------------

// fused: xb cast + weight transpose/cast + degree histogram.
// counts[] zeroed by hipMemsetAsync before this kernel.
__global__ __launch_bounds__(256) void k_pre(const float* __restrict__ x,
                                             const float* __restrict__ Whw,
                                             const float* __restrict__ Wnw,
                                             const float* __restrict__ ftw,
                                             const int* __restrict__ eidx,
                                             u16* __restrict__ xb,
                                             u32* __restrict__ counts,
                                             u16* __restrict__ Whtb,
                                             u16* __restrict__ WnAT,
                                             u16* __restrict__ WnBT,
                                             u16* __restrict__ fttb) {
    if (blockIdx.x < 20000) {
        int i = blockIdx.x * 256 + threadIdx.x;   // covers N*IN_DIM exactly
        xb[i] = f2bf(x[i]);
    } else if (blockIdx.x < 20224) {
        int i = (blockIdx.x - 20000) * 256 + threadIdx.x;   // 224*256 = 57344
        if (i < 8192) {
            int h = i >> 6, k = i & 63;
            Whtb[i] = f2bf(Whw[k * HID + h]);
        } else if (i < 24576) {
            int j = i - 8192, h = j >> 7, k = j & 127;
            WnAT[j] = f2bf(Wnw[k * HID + h]);
        } else if (i < 40960) {
            int j = i - 24576, h = j >> 7, k = j & 127;
            WnBT[j] = f2bf(Wnw[(IN_DIM + k) * HID + h]);
        } else {
            int j = i - 40960, h = j >> 7, k = j & 127;
            fttb[j] = f2bf(ftw[k * IN_DIM + h]);
        }
    } else {   // histogram: E exactly (2500 blocks)
        int e = (blockIdx.x - 20224) * 256 + threadIdx.x;
        atomicAdd(&counts[eidx[e]], 1u);
    }
}

__global__ __launch_bounds__(1024) void k_scan(const u32* __restrict__ counts,
                                               u32* __restrict__ off,
                                               u32* __restrict__ cur) {
    __shared__ u32 sums[1024];
    const int t = threadIdx.x;
    const int CH = 40;
    u32 local[CH];
    u32 s = 0;
    const int base = t * CH;
#pragma unroll
    for (int i = 0; i < CH; ++i) {
        int idx = base + i;
        u32 c = (idx < N_NODES) ? counts[idx] : 0u;
        local[i] = s;
        s += c;
    }
    sums[t] = s;
    __syncthreads();
    for (int o = 1; o < 1024; o <<= 1) {
        u32 v = (t >= o) ? sums[t - o] : 0u;
        __syncthreads();
        sums[t] += v;
        __syncthreads();
    }
    const u32 pre = sums[t] - s;
#pragma unroll
    for (int i = 0; i < CH; ++i) {
        int idx = base + i;
        if (idx < N_NODES) {
            u32 v = pre + local[i];
            off[idx] = v;
            cur[idx] = v;
        }
    }
    if (t == 1023) off[N_NODES] = sums[1023];
}

// MFMA node projection: P1 = xb@WnA + (Whb+Wnb), P2 = xb@WnB  (bf16 out)
__global__ __launch_bounds__(256) void k_proj(const u16* __restrict__ xb,
                                              const u16* __restrict__ WnAT,
                                              const u16* __restrict__ WnBT,
                                              const float* __restrict__ Whb,
                                              const float* __restrict__ Wnb,
                                              u16* __restrict__ P1b,
                                              u16* __restrict__ P2b) {
    const int t = threadIdx.x, w = t >> 6, lane = t & 63;
    const int mrow = lane & 15, quad = lane >> 4;
    const int rowBase = blockIdx.x * 64 + w * 16;

    bf16x8 a[4];
    const u16* ar = xb + (size_t)(rowBase + mrow) * IN_DIM + quad * 8;
#pragma unroll
    for (int ks = 0; ks < 4; ++ks) a[ks] = *(const bf16x8*)(ar + ks * 32);

#pragma unroll
    for (int nt = 0; nt < 8; ++nt) {
        const u16* b1p = WnAT + (size_t)(nt * 16 + mrow) * IN_DIM + quad * 8;
        const u16* b2p = WnBT + (size_t)(nt * 16 + mrow) * IN_DIM + quad * 8;
        f32x4 c1 = {0.f, 0.f, 0.f, 0.f}, c2 = {0.f, 0.f, 0.f, 0.f};
#pragma unroll
        for (int ks = 0; ks < 4; ++ks) {
            c1 = __builtin_amdgcn_mfma_f32_16x16x32_bf16(a[ks], *(const bf16x8*)(b1p + ks * 32), c1, 0, 0, 0);
            c2 = __builtin_amdgcn_mfma_f32_16x16x32_bf16(a[ks], *(const bf16x8*)(b2p + ks * 32), c2, 0, 0, 0);
        }
        const int col = nt * 16 + mrow;
        const float bias = Whb[col] + Wnb[col];
#pragma unroll
        for (int r = 0; r < 4; ++r) {
            int row = rowBase + quad * 4 + r;
            P1b[(size_t)row * HID + col] = f2bf(c1[r] + bias);
            P2b[(size_t)row * HID + col] = f2bf(c2[r]);
        }
    }
}

// PERSISTENT wave-autonomous MFMA edge kernel + fused CSR fill.
// Each wave processes 4 batches of 16 edges with NEXT-BATCH eidx PREFETCH:
// the ~500cy eidx round-trip of batch i+1 hides under batch i's gather+MFMA.
// R9 config otherwise: NT ea loads (keep 20 MB P tables L2-resident), R0
// mrow==0 4x4-serial CSR fill, per-wave partials via plain store.
__global__ __launch_bounds__(256) void k_edge(const int* __restrict__ eidx,
                                              const float* __restrict__ ea,
                                              const u16* __restrict__ Whtb,
                                              const u16* __restrict__ P1b,
                                              const u16* __restrict__ P2b,
                                              const float* __restrict__ we,
                                              u32* __restrict__ cur,
                                              uint2* __restrict__ sde,
                                              float* __restrict__ partials) {
    __shared__ u32 Psp[4][16][68];   // per-wave slices; stride 68 breaks pow2 banks
    const int t = threadIdx.x, w = t >> 6, lane = t & 63;
    const int mrow = lane & 15, quad = lane >> 4;
    const int m = lane >> 2, c4 = lane & 3;   // lane -> edge m, quarter c4
    const int wid = blockIdx.x * 4 + w;

    int e0 = wid * 16;
    // --- prefetch batch 0's eidx ---
    int srcN = eidx[e0 + m];
    int dstN = eidx[E_EDGES + e0 + m];

    float s4 = 0.f;

#pragma unroll 1
    for (int iter = 0; iter < 4; ++iter) {
        const int srcm = srcN, dstm = dstN;
        const int e0c = e0;

        // --- prefetch NEXT batch's eidx (4 regs) — hides under this batch ---
        if (iter < 3) {
            srcN = eidx[e0 + ESTEP + m];
            dstN = eidx[E_EDGES + e0 + ESTEP + m];
        }
        e0 += ESTEP;

        // --- issue gathers + ea stream for current batch ---
        const uint4* p1 = (const uint4*)(P1b + (size_t)srcm * HID + c4 * 32);
        const uint4* p2 = (const uint4*)(P2b + (size_t)dstm * HID + c4 * 32);
        uint4 pa[4], pb[4];
#pragma unroll
        for (int i = 0; i < 4; ++i) { pa[i] = p1[i]; pb[i] = p2[i]; }

        const f32x4* arow = (const f32x4*)(ea + (size_t)(e0c + mrow) * EDGE_DIM + quad * 8);
        f32x4 f0 = __builtin_nontemporal_load(arow);       // +0
        f32x4 f1 = __builtin_nontemporal_load(arow + 1);   // +4
        f32x4 f2 = __builtin_nontemporal_load(arow + 8);   // +32
        f32x4 f3 = __builtin_nontemporal_load(arow + 9);   // +36

        // --- pack node term into this wave's LDS slice ---
#pragma unroll
        for (int i = 0; i < 4; ++i) {
            u32 da[4] = {pa[i].x, pa[i].y, pa[i].z, pa[i].w};
            u32 db[4] = {pb[i].x, pb[i].y, pb[i].z, pb[i].w};
            uint4 o;
            o.x = pack_bf(bf_lo(da[0]) + bf_lo(db[0]), bf_hi(da[0]) + bf_hi(db[0]));
            o.y = pack_bf(bf_lo(da[1]) + bf_lo(db[1]), bf_hi(da[1]) + bf_hi(db[1]));
            o.z = pack_bf(bf_lo(da[2]) + bf_lo(db[2]), bf_hi(da[2]) + bf_hi(db[2]));
            o.w = pack_bf(bf_lo(da[3]) + bf_lo(db[3]), bf_hi(da[3]) + bf_hi(db[3]));
            *(uint4*)&Psp[w][m][c4 * 16 + i * 4] = o;
        }

        // --- A fragments from f0..f3 ---
        bf16x8 a0, a1;
        a0[0] = (short)f2bf(f0[0]); a0[1] = (short)f2bf(f0[1]);
        a0[2] = (short)f2bf(f0[2]); a0[3] = (short)f2bf(f0[3]);
        a0[4] = (short)f2bf(f1[0]); a0[5] = (short)f2bf(f1[1]);
        a0[6] = (short)f2bf(f1[2]); a0[7] = (short)f2bf(f1[3]);
        a1[0] = (short)f2bf(f2[0]); a1[1] = (short)f2bf(f2[1]);
        a1[2] = (short)f2bf(f2[2]); a1[3] = (short)f2bf(f2[3]);
        a1[4] = (short)f2bf(f3[0]); a1[5] = (short)f2bf(f3[1]);
        a1[6] = (short)f2bf(f3[2]); a1[7] = (short)f2bf(f3[3]);

        // --- MFMA over 8 n-tiles; fuse +Psum, relu, *we ---
        float wsum[4] = {0.f, 0.f, 0.f, 0.f};
        const u16* bbase = Whtb + (size_t)mrow * EDGE_DIM + quad * 8;
#pragma unroll
        for (int nt = 0; nt < 8; ++nt) {
            const u16* bp = bbase + nt * 16 * EDGE_DIM;
            bf16x8 b0 = *(const bf16x8*)(bp);
            bf16x8 b1 = *(const bf16x8*)(bp + 32);
            f32x4 c = {0.f, 0.f, 0.f, 0.f};
            c = __builtin_amdgcn_mfma_f32_16x16x32_bf16(a0, b0, c, 0, 0, 0);
            c = __builtin_amdgcn_mfma_f32_16x16x32_bf16(a1, b1, c, 0, 0, 0);
            float wv = we[nt * 16 + mrow];
#pragma unroll
            for (int r = 0; r < 4; ++r) {
                u32 u = Psp[w][quad * 4 + r][nt * 8 + (mrow >> 1)];
                float p = (mrow & 1) ? bf_hi(u) : bf_lo(u);
                wsum[r] += fmaxf(c[r] + p, 0.f) * wv;
            }
        }

        // --- reduce across the 16 lanes of each quad group ---
#pragma unroll
        for (int off = 1; off < 16; off <<= 1) {
#pragma unroll
            for (int r = 0; r < 4; ++r) wsum[r] += __shfl_xor(wsum[r], off, 16);
        }
        float ex[4];
#pragma unroll
        for (int r = 0; r < 4; ++r) { ex[r] = __expf(wsum[r]); s4 += ex[r]; }

        // --- fused CSR fill: R0 exact pattern (mrow==0 lanes, 4 serial each) ---
        if (mrow == 0) {
#pragma unroll
            for (int r = 0; r < 4; ++r) {
                int e = e0c + quad * 4 + r;
                int s = eidx[e];
                int d = eidx[E_EDGES + e];
                u32 pos = atomicAdd(&cur[s], 1u);
                sde[pos] = make_uint2((u32)d, __float_as_uint(-ex[r]));
            }
        }
    }

    // --- per-wave partial over all 4 batches (plain store, no atomics) ---
    s4 += __shfl_xor(s4, 16, 64);
    s4 += __shfl_xor(s4, 32, 64);
    if (lane == 0) partials[wid] = s4;
}

// block 0: reduce partials -> sumExp. blocks 1..N/4: one WAVE per node,
// out[n][:] = sum_{edges of n} (-exp_e) * xb[dst][:]   (RAW — invS in k_final)
// Gather shape: four 16-lane groups each fetch a DIFFERENT edge row at
// 16 B/lane (uint4) — one instruction = 4 rows (1 KB) vs 1 row (256 B).
__global__ __launch_bounds__(256) void k_accum(const u32* __restrict__ off,
                                               const uint2* __restrict__ sde,
                                               const float* __restrict__ partials,
                                               float* __restrict__ sumExp,
                                               const u16* __restrict__ xb,
                                               float* __restrict__ out) {
    if (blockIdx.x == 0) {   // fused k_sum (saves a launch)
        float s = 0.f;
        for (int i = threadIdx.x; i < NPART; i += 256) s += partials[i];
#pragma unroll
        for (int o = 1; o < 64; o <<= 1) s += __shfl_xor(s, o, 64);
        __shared__ float ws4[4];
        if ((threadIdx.x & 63) == 0) ws4[threadIdx.x >> 6] = s;
        __syncthreads();
        if (threadIdx.x == 0) sumExp[0] = ws4[0] + ws4[1] + ws4[2] + ws4[3];
        return;
    }
    const int lane = threadIdx.x & 63;
    const int g = lane >> 4, sub = lane & 15;   // group 0..3, 16 lanes each
    const int n = (blockIdx.x - 1) * 4 + (threadIdx.x >> 6);
    const u32 o0 = off[n], o1 = off[n + 1];

    float acc[8] = {0.f, 0.f, 0.f, 0.f, 0.f, 0.f, 0.f, 0.f};

    for (u32 base = o0; base < o1; base += 64) {
        u32 j = base + (u32)lane;
        uint2 dv = make_uint2(0u, 0u);     // zeroed => row 0, weight +0.0
        if (j < o1) {
            dv.x = __builtin_nontemporal_load(&sde[j].x);
            dv.y = __builtin_nontemporal_load(&sde[j].y);
        }
        const int cnt = (int)min(64u, o1 - base);
        for (int jj = 0; jj < cnt; jj += 16) {   // 4 quads of 4 rows in flight
            float av[4]; uint4 q[4];
#pragma unroll
            for (int b = 0; b < 4; ++b) {
                int sl = jj + b * 4 + g;          // <= 63 always
                u32 dr = __shfl(dv.x, sl, 64);
                av[b] = __uint_as_float(__shfl(dv.y, sl, 64));
                q[b] = ((const uint4*)(xb + (size_t)dr * IN_DIM))[sub];
            }
#pragma unroll
            for (int b = 0; b < 4; ++b) {
                acc[0] = fmaf(av[b], bf_lo(q[b].x), acc[0]);
                acc[1] = fmaf(av[b], bf_hi(q[b].x), acc[1]);
                acc[2] = fmaf(av[b], bf_lo(q[b].y), acc[2]);
                acc[3] = fmaf(av[b], bf_hi(q[b].y), acc[3]);
                acc[4] = fmaf(av[b], bf_lo(q[b].z), acc[4]);
                acc[5] = fmaf(av[b], bf_hi(q[b].z), acc[5]);
                acc[6] = fmaf(av[b], bf_lo(q[b].w), acc[6]);
                acc[7] = fmaf(av[b], bf_hi(q[b].w), acc[7]);
            }
        }
    }

    // fold the 4 group-partials (lanes l, l^16, l^32, l^48 share columns)
#pragma unroll
    for (int k = 0; k < 8; ++k) {
        acc[k] += __shfl_xor(acc[k], 16, 64);
        acc[k] += __shfl_xor(acc[k], 32, 64);
    }
    if (g == 0) {   // lanes 0..15 write the 128-float row (two float4 each)
        float* op = out + (size_t)n * IN_DIM + sub * 8;
        float4 v0 = make_float4(acc[0], acc[1], acc[2], acc[3]);
        float4 v1 = make_float4(acc[4], acc[5], acc[6], acc[7]);
        *(float4*)op = v0;
        *(float4*)(op + 4) = v1;
    }
}

// MFMA finisher: out = y + y@ft + ftb, y = x + invS*local_raw(out in-place).
__global__ __launch_bounds__(256) void k_final(const float* __restrict__ x,
                                               const u16* __restrict__ fttb,
                                               const float* __restrict__ ftb,
                                               const float* __restrict__ sumExp,
                                               float* __restrict__ out) {
    __shared__ u32 ybp[64][68];   // packed bf16 y
    const float invS = 1.0f / sumExp[0];
    const int t = threadIdx.x;
    const int rb = blockIdx.x * 64;

    {   // stage y = x + invS*local as packed bf16
        const int rr = t >> 2, seg = t & 3;
        const float4* xp = (const float4*)(x + (size_t)(rb + rr) * IN_DIM + seg * 32);
        const float4* lp = (const float4*)(out + (size_t)(rb + rr) * IN_DIM + seg * 32);
#pragma unroll
        for (int i = 0; i < 4; ++i) {
            float4 xa = xp[2 * i], xc = xp[2 * i + 1];
            float4 la = lp[2 * i], lc = lp[2 * i + 1];
            uint4 o;
            o.x = pack_bf(fmaf(invS, la.x, xa.x), fmaf(invS, la.y, xa.y));
            o.y = pack_bf(fmaf(invS, la.z, xa.z), fmaf(invS, la.w, xa.w));
            o.z = pack_bf(fmaf(invS, lc.x, xc.x), fmaf(invS, lc.y, xc.y));
            o.w = pack_bf(fmaf(invS, lc.z, xc.z), fmaf(invS, lc.w, xc.w));
            *(uint4*)&ybp[rr][seg * 16 + i * 4] = o;
        }
    }
    __syncthreads();

    const int w = t >> 6, lane = t & 63;
    const int mrow = lane & 15, quad = lane >> 4;
    const int rowBase = rb + w * 16;

    bf16x8 a[4];
#pragma unroll
    for (int ks = 0; ks < 4; ++ks)
        a[ks] = *(const bf16x8*)&ybp[w * 16 + mrow][ks * 16 + quad * 4];

#pragma unroll
    for (int nt = 0; nt < 8; ++nt) {
        const u16* bp = fttb + (size_t)(nt * 16 + mrow) * IN_DIM + quad * 8;
        f32x4 c = {0.f, 0.f, 0.f, 0.f};
#pragma unroll
        for (int ks = 0; ks < 4; ++ks)
            c = __builtin_amdgcn_mfma_f32_16x16x32_bf16(a[ks], *(const bf16x8*)(bp + ks * 32), c, 0, 0, 0);
        const int col = nt * 16 + mrow;
        const float fb = ftb[col];
#pragma unroll
        for (int r = 0; r < 4; ++r) {
            int row = rowBase + quad * 4 + r;
            size_t idx = (size_t)row * IN_DIM + col;
            float y = fmaf(invS, out[idx], x[idx]);   // exact fp32 y term
            out[idx] = y + c[r] + fb;
        }
    }
}

extern "C" void kernel_launch(void* const* d_in, const int* in_sizes, int n_in,
                              void* d_out, int out_size, void* d_ws, size_t ws_size,
                              hipStream_t stream) {
    const float* x    = (const float*)d_in[0];
    const int*   eidx = (const int*)d_in[1];
    const float* ea   = (const float*)d_in[2];
    const float* Whw  = (const float*)d_in[3];
    const float* Whb  = (const float*)d_in[4];
    const float* Wnw  = (const float*)d_in[5];
    const float* Wnb  = (const float*)d_in[6];
    const float* we   = (const float*)d_in[7];
    const float* ftw  = (const float*)d_in[8];
    const float* ftb  = (const float*)d_in[9];
    float* out = (float*)d_out;

    uint2* sde      = (uint2*)d_ws;                       // 8-B aligned first
    u16*   P1b      = (u16*)(sde + (size_t)E_EDGES);
    u16*   P2b      = P1b + (size_t)N_NODES * HID;
    u16*   xb       = P2b + (size_t)N_NODES * HID;
    u16*   Whtb     = xb + (size_t)N_NODES * IN_DIM;
    u16*   WnAT     = Whtb + (size_t)EDGE_DIM * HID;
    u16*   WnBT     = WnAT + (size_t)HID * IN_DIM;
    u16*   fttb     = WnBT + (size_t)HID * IN_DIM;
    float* partials = (float*)(fttb + (size_t)IN_DIM * IN_DIM);
    float* sumExp   = partials + NPART;
    u32*   counts   = (u32*)(sumExp + 1);
    u32*   off      = counts + N_NODES;
    u32*   cur      = off + N_NODES + 1;

    hipMemsetAsync(counts, 0, (size_t)N_NODES * sizeof(u32), stream);
    k_pre  <<<22724, 256, 0, stream>>>(x, Whw, Wnw, ftw, eidx, xb, counts,
                                       Whtb, WnAT, WnBT, fttb);
    k_scan <<<1, 1024, 0, stream>>>(counts, off, cur);
    k_proj <<<N_NODES / 64, 256, 0, stream>>>(xb, WnAT, WnBT, Whb, Wnb, P1b, P2b);
    k_edge <<<EBP, 256, 0, stream>>>(eidx, ea, Whtb, P1b, P2b, we, cur, sde, partials);
    k_accum<<<N_NODES / 4 + 1, 256, 0, stream>>>(off, sde, partials, sumExp, xb, out);
    k_final<<<N_NODES / 64, 256, 0, stream>>>(x, fttb, ftb, sumExp, out);
}